// Round 5
// baseline (86.564 us; speedup 1.0000x reference)
//
#include <hip/hip_runtime.h>
#include <math.h>

// RationalQuadraticSpline: B=65536, V=64, K=30 bins. TWO kernels.
// History: R8 fused +11us (prologue on DS pipe). R9 (3 DS ops, 16 waves)
// 87.6. R10 (32 waves, VGPR<=64) 85.3 -- occupancy doubling bought only
// 2.3us => waves x ILP product was constant (VGPR cap halved per-wave ILP).
// R11 (this, re-run after infra failure): trade waves for ILP: 16 waves/CU,
// VGPR<=128, and an EXPLICIT 8-element software pipeline per thread (both
// grid-stride iterations unrolled): all x loads -> all 8 LUT ds_read_b32 ->
// all 8 rec b128 + der read2 -> all VALU -> 4 float4 stores. Exposed LDS
// latency ~2 round trips PER THREAD instead of per 4-element group.
// (Delta vs failed run: nontemporal stores -> plain stores; marginal hint,
// removes the only unusual builtin in the diff.)
//
// LDS/P layout (dwords):
//   rec: [0, 7936)      stride 124/var, 30 recs x4 {cumw, 1/w, cumh, h}
//   der: [7936, 9920)   stride 31/var, d[0..30]
//   lut: [9920, 18432)  u32 {frac:16, lo:8}, stride 133/var, 128 buckets
// Total 73728 B -> 2 blocks/CU x 16 waves = 16 waves/CU.
// LUT exactness: min bin width >= 0.01316 > 1/128 -> <=1 knot per bucket;
// probe = (u + (frac+1)/65536)/128 exact in f32 (7+16 <= 23 mantissa bits).

#define NB 65536
#define NV 64
#define NKB 30
#define REC_D 124
#define DER_BASE 7936
#define DER_S 31
#define LUTD_BASE 9920
#define LUT_S 133
#define TOT_D 18432
#define GRID 512
#define BSZ 1024

__global__ __launch_bounds__(64) void rqs_params(const float* __restrict__ uw,
                                                 const float* __restrict__ uh,
                                                 const float* __restrict__ ud,
                                                 float* __restrict__ P) {
  const int v = blockIdx.x;
  const int lane = threadIdx.x;
  const float MINB = 1e-3f;
  const float scale = 1.0f - MINB * (float)NKB;

  // ---- widths: softmax + floor + scan (all shuffles full-wave) ----
  float cw_e, winv, wnxt;
  {
    float u = (lane < NKB) ? uw[v * NKB + lane] : -1e30f;
    float m = u;
#pragma unroll
    for (int s = 32; s >= 1; s >>= 1) m = fmaxf(m, __shfl_xor(m, s));
    float e = (lane < NKB) ? expf(u - m) : 0.0f;
    float t = e;
#pragma unroll
    for (int s = 32; s >= 1; s >>= 1) t += __shfl_xor(t, s);
    float pk = (lane < NKB) ? (MINB + scale * (e / t)) : 0.0f;
    float ci = pk;
#pragma unroll
    for (int s = 1; s < 64; s <<= 1) {
      float z = __shfl_up(ci, s);
      if (lane >= s) ci += z;
    }
    cw_e = ci - pk;                            // cumw[lane] (exclusive)
    wnxt = (lane == NKB - 1) ? 1.0f : ci;      // cumw[lane+1], forced hi
    winv = 1.0f / (wnxt - cw_e);
  }
  // ---- heights ----
  float ch_e, hh;
  {
    float u = (lane < NKB) ? uh[v * NKB + lane] : -1e30f;
    float m = u;
#pragma unroll
    for (int s = 32; s >= 1; s >>= 1) m = fmaxf(m, __shfl_xor(m, s));
    float e = (lane < NKB) ? expf(u - m) : 0.0f;
    float t = e;
#pragma unroll
    for (int s = 32; s >= 1; s >>= 1) t += __shfl_xor(t, s);
    float pk = (lane < NKB) ? (MINB + scale * (e / t)) : 0.0f;
    float ci = pk;
#pragma unroll
    for (int s = 1; s < 64; s <<= 1) {
      float z = __shfl_up(ci, s);
      if (lane >= s) ci += z;
    }
    ch_e = ci - pk;
    float hnxt = (lane == NKB - 1) ? 1.0f : ci;
    hh = hnxt - ch_e;
  }
  // ---- packed records ----
  if (lane < NKB) {
    float4 r = {cw_e, winv, ch_e, hh};
    *(float4*)(P + v * REC_D + 4 * lane) = r;
  }
  // ---- derivatives: pad with CONST so softplus(CONST)+MIN_D == 1 ----
  {
    const float CST = (float)log(exp(1.0 - 1e-3) - 1.0);
    if (lane <= NKB) {
      float x = (lane == 0 || lane == NKB) ? CST : ud[v * (NKB - 1) + lane - 1];
      float sp = (x > 0.f) ? (x + log1pf(expf(-x))) : log1pf(expf(x));
      P[DER_BASE + v * DER_S + lane] = 1e-3f + sp;
    }
  }
  // ---- fused LUT: bucket ub -> {frac:16, lo:8} ----
  //   lo   = #{k in [1..29]: cumw[k] <= ub/128}
  //   main decodes probe = (ub + (frac+1)/65536)/128 (exact f32), with
  //   knot < probe <= knot + 1.2e-7; C1 continuity makes the window harmless.
  {
    float t0 = (float)lane * (1.0f / 128.0f);
    float t1 = (float)(lane + 64) * (1.0f / 128.0f);
    int lo0 = 0, lo1 = 0;
#pragma unroll
    for (int kk = 0; kk < NKB - 1; ++kk) {     // k = 1..29 (cumw[30]=1 > t)
      float c = __shfl(wnxt, kk);              // cumw[kk+1]; full-wave shuffle
      lo0 += (c <= t0) ? 1 : 0;
      lo1 += (c <= t1) ? 1 : 0;
    }
    float k0 = __shfl(wnxt, lo0);              // cumw[lo0+1], lo0 <= 29
    float k1 = __shfl(wnxt, lo1);
    unsigned int* Pu = (unsigned int*)P;
    {
      float top = (float)(lane + 1) * (1.0f / 128.0f);
      int frac = 65535;
      if (k0 < top) {
        frac = (int)((k0 * 128.0f - (float)lane) * 65536.0f);
        frac = frac > 65535 ? 65535 : frac;
      }
      Pu[LUTD_BASE + v * LUT_S + lane] =
          ((unsigned int)frac << 16) | (unsigned int)lo0;
    }
    {
      float top = (float)(lane + 65) * (1.0f / 128.0f);
      int frac = 65535;
      if (k1 < top) {
        frac = (int)((k1 * 128.0f - (float)(lane + 64)) * 65536.0f);
        frac = frac > 65535 ? 65535 : frac;
      }
      Pu[LUTD_BASE + v * LUT_S + lane + 64] =
          ((unsigned int)frac << 16) | (unsigned int)lo1;
    }
  }
}

__global__ __launch_bounds__(BSZ, 4) void rqs_main(const float* __restrict__ x,
                                                   const float* __restrict__ P,
                                                   float* __restrict__ out) {
  __shared__ __align__(16) float lds[TOT_D];  // 73728 B -> 2 blocks/CU
  for (int i = threadIdx.x; i < TOT_D / 4; i += BSZ)
    ((float4*)lds)[i] = ((const float4*)P)[i];
  __syncthreads();
  const unsigned int* lutu = (const unsigned int*)lds;

  const int N = NB * NV;
  const int gid0 = blockIdx.x * BSZ + threadIdx.x;
  const int gid1 = gid0 + GRID * BSZ;          // second (and last) iteration
  const int v0 = (gid0 & 15) * 4;              // same for gid1 (stride%16==0)
  const int bR = v0 * REC_D;
  const int bD = DER_BASE + v0 * DER_S;
  const int bL = LUTD_BASE + v0 * LUT_S;

  // ---- phase 0: both x vectors ----
  float4 xv0 = ((const float4*)x)[gid0];
  float4 xv1 = ((const float4*)x)[gid1];
  float xs[8] = {xv0.x, xv0.y, xv0.z, xv0.w, xv1.x, xv1.y, xv1.z, xv1.w};

  // ---- phase 1: all 8 LUT reads in flight ----
  unsigned int en[8];
#pragma unroll
  for (int e = 0; e < 8; ++e) {
    const int j = e & 3;
    float xx = xs[e];
    int ui = (int)(xx * 128.0f);  // exact: x * 2^7
    ui = ui < 0 ? 0 : (ui > 127 ? 127 : ui);
    en[e] = lutu[bL + j * LUT_S + ui];                   // ds_read_b32
  }

  // ---- phase 2: all 8 bin resolves + table reads in flight ----
  float4 r4[8];
  float d0[8], d1[8];
#pragma unroll
  for (int e = 0; e < 8; ++e) {
    const int j = e & 3;
    float xx = xs[e];
    int ui = (int)(xx * 128.0f);  // recompute (2 VALU) cheaper than 8 regs
    ui = ui < 0 ? 0 : (ui > 127 ? 127 : ui);
    unsigned int enx = en[e];
    int lo = (int)(enx & 0xFFu);
    float probe = ((float)ui + (float)((enx >> 16) + 1u) * (1.0f / 65536.0f)) *
                  (1.0f / 128.0f);
    int b = lo + ((xx >= probe) ? 1 : 0);
    b = b > 29 ? 29 : b;
    r4[e] = *(const float4*)&lds[bR + j * REC_D + 4 * b]; // ds_read_b128
    d0[e] = lds[bD + j * DER_S + b];                      // ds_read2_b32
    d1[e] = lds[bD + j * DER_S + b + 1];
  }

  // ---- phase 3: all VALU ----
  float o[8], l[8];
#pragma unroll
  for (int e = 0; e < 8; ++e) {
    float xx = xs[e];
    float icw = r4[e].x, winv = r4[e].y, ich = r4[e].z, ih = r4[e].w;
    float idl  = ih * winv;  // delta = h/w
    float thx  = (xx - icw) * winv;
    float omt  = 1.0f - thx;
    float t1mt = thx * omt;
    float th2  = thx * thx;
    float num  = ih * (idl * th2 + d0[e] * t1mt);
    float den  = idl + (d0[e] + d1[e] - 2.0f * idl) * t1mt;
    float rden = __builtin_amdgcn_rcpf(den);  // v_rcp_f32
    float so   = ich + num * rden;
    float dn   = idl * idl * (d1[e] * th2 + 2.0f * idl * t1mt + d0[e] * omt * omt);
    float sl   = __logf(dn * rden * rden);    // log(dn) - 2*log(den)
    bool inside = !(xx < 0.0f) && !(xx > 1.0f);
    o[e] = inside ? so : xx;   // DERIV_OUT = 1 -> identity outside
    l[e] = inside ? sl : 0.0f;
  }

  // ---- phase 4: stores ----
  float4 ov0 = {o[0], o[1], o[2], o[3]};
  float4 lv0 = {l[0], l[1], l[2], l[3]};
  float4 ov1 = {o[4], o[5], o[6], o[7]};
  float4 lv1 = {l[4], l[5], l[6], l[7]};
  ((float4*)out)[gid0] = ov0;
  ((float4*)(out + N))[gid0] = lv0;
  ((float4*)out)[gid1] = ov1;
  ((float4*)(out + N))[gid1] = lv1;
}

extern "C" void kernel_launch(void* const* d_in, const int* in_sizes, int n_in,
                              void* d_out, int out_size, void* d_ws, size_t ws_size,
                              hipStream_t stream) {
  const float* x  = (const float*)d_in[0];
  const float* uw = (const float*)d_in[1];
  const float* uh = (const float*)d_in[2];
  const float* ud = (const float*)d_in[3];
  float* out = (float*)d_out;
  float* P   = (float*)d_ws;  // 73728 B used

  rqs_params<<<NV, 64, 0, stream>>>(uw, uh, ud, P);
  rqs_main<<<GRID, BSZ, 0, stream>>>(x, P, out);
}

// Round 7
// 86.448 us; speedup vs baseline: 1.0013x; 1.0013x over previous
//
#include <hip/hip_runtime.h>
#include <math.h>

// RationalQuadraticSpline: B=65536, V=64, K=30 bins. TWO kernels.
// History: R8 fused +11us. R9 (3 DS ops, 16 waves) 87.6. R10 (32 waves,
// VGPR<=64) 85.3. R11 (explicit 8-deep pipeline) 86.6. R12 (bank twist)
// FAILED 0.826: (a) base-twist overflowed var slots at the tw wrap v=31->32
// (concurrent blocks clobbered 6 records), (b) "fb > frac" probe rule
// wrongly bumped the top 2^-16 sliver of knotless buckets.
// R13 = R12 theory, both bugs fixed:
//   (a) twist is now a ROTATION inside each var's 120-dword record region:
//       slot = (4b + tw) mod 120, tw = 4*((v>>2)&7). Never leaves the var's
//       124-dword slot; 16B alignment kept; params/main share the formula.
//       Bank spread unchanged: base col 16k + 4(k&7) mod 32 covers all 8
//       quad-columns over k=lane&15 (was 2 of 8 -> est ~1.7x conflict on
//       the dominant ds_read_b128).
//   (b) bump iff fb >= (float)(frac+1)  -- bit-exact with R9..R11 verified
//       semantics (fb < 65536 always, so knotless buckets never bump).
//
// LDS/P layout (dwords), identical footprint to R11:
//   rec: [0, 7936)      stride 124/var, 30 recs x4 {cumw,1/w,cumh,h}, rotated
//   der: [7936, 9920)   stride 31/var, d[0..30]
//   lut: [9920, 18432)  u32 {frac:16, lo:8}, stride 133/var, 128 buckets
// Total 73728 B -> 2 blocks/CU x 16 waves = 32 waves/CU.
// LUT exactness: min bin width >= 0.01316 > 1/128 -> <=1 knot per bucket.

#define NB 65536
#define NV 64
#define NKB 30
#define REC_D 124
#define DER_BASE 7936
#define DER_S 31
#define LUTD_BASE 9920
#define LUT_S 133
#define TOT_D 18432
#define GRID 512
#define BSZ 1024
#define REC_TW(v) ((((v) >> 2) & 7) << 2)  // per-var rotation, dwords

__global__ __launch_bounds__(64) void rqs_params(const float* __restrict__ uw,
                                                 const float* __restrict__ uh,
                                                 const float* __restrict__ ud,
                                                 float* __restrict__ P) {
  const int v = blockIdx.x;
  const int lane = threadIdx.x;
  const float MINB = 1e-3f;
  const float scale = 1.0f - MINB * (float)NKB;

  // ---- widths: softmax + floor + scan (all shuffles full-wave) ----
  float cw_e, winv, wnxt;
  {
    float u = (lane < NKB) ? uw[v * NKB + lane] : -1e30f;
    float m = u;
#pragma unroll
    for (int s = 32; s >= 1; s >>= 1) m = fmaxf(m, __shfl_xor(m, s));
    float e = (lane < NKB) ? expf(u - m) : 0.0f;
    float t = e;
#pragma unroll
    for (int s = 32; s >= 1; s >>= 1) t += __shfl_xor(t, s);
    float pk = (lane < NKB) ? (MINB + scale * (e / t)) : 0.0f;
    float ci = pk;
#pragma unroll
    for (int s = 1; s < 64; s <<= 1) {
      float z = __shfl_up(ci, s);
      if (lane >= s) ci += z;
    }
    cw_e = ci - pk;                            // cumw[lane] (exclusive)
    wnxt = (lane == NKB - 1) ? 1.0f : ci;      // cumw[lane+1], forced hi
    winv = 1.0f / (wnxt - cw_e);
  }
  // ---- heights ----
  float ch_e, hh;
  {
    float u = (lane < NKB) ? uh[v * NKB + lane] : -1e30f;
    float m = u;
#pragma unroll
    for (int s = 32; s >= 1; s >>= 1) m = fmaxf(m, __shfl_xor(m, s));
    float e = (lane < NKB) ? expf(u - m) : 0.0f;
    float t = e;
#pragma unroll
    for (int s = 32; s >= 1; s >>= 1) t += __shfl_xor(t, s);
    float pk = (lane < NKB) ? (MINB + scale * (e / t)) : 0.0f;
    float ci = pk;
#pragma unroll
    for (int s = 1; s < 64; s <<= 1) {
      float z = __shfl_up(ci, s);
      if (lane >= s) ci += z;
    }
    ch_e = ci - pk;
    float hnxt = (lane == NKB - 1) ? 1.0f : ci;
    hh = hnxt - ch_e;
  }
  // ---- packed records (rotated slot within the var's 120-dword region) ----
  if (lane < NKB) {
    int idx = 4 * lane + REC_TW(v);
    if (idx >= 120) idx -= 120;
    float4 r = {cw_e, winv, ch_e, hh};
    *(float4*)(P + v * REC_D + idx) = r;
  }
  // ---- derivatives: pad with CONST so softplus(CONST)+MIN_D == 1 ----
  {
    const float CST = (float)log(exp(1.0 - 1e-3) - 1.0);
    if (lane <= NKB) {
      float x = (lane == 0 || lane == NKB) ? CST : ud[v * (NKB - 1) + lane - 1];
      float sp = (x > 0.f) ? (x + log1pf(expf(-x))) : log1pf(expf(x));
      P[DER_BASE + v * DER_S + lane] = 1e-3f + sp;
    }
  }
  // ---- fused LUT: bucket ub -> {frac:16, lo:8} ----
  //   lo   = #{k in [1..29]: cumw[k] <= ub/128}
  //   main bumps iff (x*128 - ub)*65536 >= frac+1 (exact f32; fb < 65536
  //   always, so frac=65535 knotless buckets never bump).
  {
    float t0 = (float)lane * (1.0f / 128.0f);
    float t1 = (float)(lane + 64) * (1.0f / 128.0f);
    int lo0 = 0, lo1 = 0;
#pragma unroll
    for (int kk = 0; kk < NKB - 1; ++kk) {     // k = 1..29 (cumw[30]=1 > t)
      float c = __shfl(wnxt, kk);              // cumw[kk+1]; full-wave shuffle
      lo0 += (c <= t0) ? 1 : 0;
      lo1 += (c <= t1) ? 1 : 0;
    }
    float k0 = __shfl(wnxt, lo0);              // cumw[lo0+1], lo0 <= 29
    float k1 = __shfl(wnxt, lo1);
    unsigned int* Pu = (unsigned int*)P;
    {
      float top = (float)(lane + 1) * (1.0f / 128.0f);
      int frac = 65535;
      if (k0 < top) {
        frac = (int)((k0 * 128.0f - (float)lane) * 65536.0f);
        frac = frac > 65535 ? 65535 : frac;
      }
      Pu[LUTD_BASE + v * LUT_S + lane] =
          ((unsigned int)frac << 16) | (unsigned int)lo0;
    }
    {
      float top = (float)(lane + 65) * (1.0f / 128.0f);
      int frac = 65535;
      if (k1 < top) {
        frac = (int)((k1 * 128.0f - (float)(lane + 64)) * 65536.0f);
        frac = frac > 65535 ? 65535 : frac;
      }
      Pu[LUTD_BASE + v * LUT_S + lane + 64] =
          ((unsigned int)frac << 16) | (unsigned int)lo1;
    }
  }
}

__global__ __launch_bounds__(BSZ, 8) void rqs_main(const float* __restrict__ x,
                                                   const float* __restrict__ P,
                                                   float* __restrict__ out) {
  __shared__ __align__(16) float lds[TOT_D];  // 73728 B -> 2 blocks/CU
  for (int i = threadIdx.x; i < TOT_D / 4; i += BSZ)
    ((float4*)lds)[i] = ((const float4*)P)[i];
  __syncthreads();
  const unsigned int* lutu = (const unsigned int*)lds;

  const int N = NB * NV;
  const int n4 = N / 4;  // 1048576 float4 groups
  const int gid0 = blockIdx.x * BSZ + threadIdx.x;
  const int v0 = (gid0 & 15) * 4;  // constant per thread (stride % 16 == 0)
  // single base per table; j*stride folds into the DS immediate offset.
  // rotation tw = REC_TW(v0) is the SAME for all j in [0,4) (v0 % 4 == 0).
  const int bR = v0 * REC_D;
  const int tw = REC_TW(v0);
  const int bD = DER_BASE + v0 * DER_S;
  const int bL = LUTD_BASE + v0 * LUT_S;

  for (int gid = gid0; gid < n4; gid += GRID * BSZ) {  // exactly 2 iters
    float4 xv = ((const float4*)x)[gid];
    float xs[4] = {xv.x, xv.y, xv.z, xv.w};
    float o[4], l[4];
#pragma unroll
    for (int j = 0; j < 4; ++j) {
      float xx = xs[j];
      float xf = xx * 128.0f;       // exact (power-of-2 scale)
      int ui = (int)xf;
      ui = ui < 0 ? 0 : (ui > 127 ? 127 : ui);
      unsigned int en = lutu[bL + j * LUT_S + ui];         // ds_read_b32
      // bump iff (xf - ui)*65536 >= frac+1  (exact f32; == R9..R11 rule)
      float fb = (xf - (float)ui) * 65536.0f;
      int b = (int)(en & 0xFFu) + ((fb >= (float)((en >> 16) + 1u)) ? 1 : 0);
      b = b > 29 ? 29 : b;          // x == 1.0 exactly
      int idx = 4 * b + tw;
      idx = (idx >= 120) ? idx - 120 : idx;                // rotation
      float4 r4 = *(const float4*)&lds[bR + j * REC_D + idx];  // ds_read_b128
      float d0 = lds[bD + j * DER_S + b];                  // ds_read2_b32
      float d1 = lds[bD + j * DER_S + b + 1];
      float icw = r4.x, winv = r4.y, ich = r4.z, ih = r4.w;
      float idl  = ih * winv;  // delta = h/w
      float thx  = (xx - icw) * winv;
      float omt  = 1.0f - thx;
      float t1mt = thx * omt;
      float th2  = thx * thx;
      float num  = ih * (idl * th2 + d0 * t1mt);
      float den  = idl + (d0 + d1 - 2.0f * idl) * t1mt;
      float rden = __builtin_amdgcn_rcpf(den);  // v_rcp_f32
      float so   = ich + num * rden;
      float dn   = idl * idl * (d1 * th2 + 2.0f * idl * t1mt + d0 * omt * omt);
      float sl   = __logf(dn * rden * rden);    // log(dn) - 2*log(den)
      bool inside = !(xx < 0.0f) && !(xx > 1.0f);
      o[j] = inside ? so : xx;   // DERIV_OUT = 1 -> identity outside
      l[j] = inside ? sl : 0.0f;
    }
    float4 ov = {o[0], o[1], o[2], o[3]};
    float4 lv = {l[0], l[1], l[2], l[3]};
    ((float4*)out)[gid] = ov;
    ((float4*)(out + N))[gid] = lv;
  }
}

extern "C" void kernel_launch(void* const* d_in, const int* in_sizes, int n_in,
                              void* d_out, int out_size, void* d_ws, size_t ws_size,
                              hipStream_t stream) {
  const float* x  = (const float*)d_in[0];
  const float* uw = (const float*)d_in[1];
  const float* uh = (const float*)d_in[2];
  const float* ud = (const float*)d_in[3];
  float* out = (float*)d_out;
  float* P   = (float*)d_ws;  // 73728 B used

  rqs_params<<<NV, 64, 0, stream>>>(uw, uh, ud, P);
  rqs_main<<<GRID, BSZ, 0, stream>>>(x, P, out);
}